// Round 4
// baseline (522.254 us; speedup 1.0000x reference)
//
#include <hip/hip_runtime.h>

#define NROWS  131072
#define DDIM   64
#define KCODES 512
#define NMAIN  1024   // NROWS / 128

// ws float offsets
#define WS_WT   0       // 32768 floats: wT[k][d]
#define WS_WSQ  32768   // 512 floats
#define WS_AUX  33280   // parts (1024 floats) or atomic cell (1 float)

__global__ void vq_prep(const float* __restrict__ w, float* __restrict__ wT,
                        float* __restrict__ wsq) {
  int g = blockIdx.x * 256 + threadIdx.x;  // g = k*64 + d, 32768 total
  wT[g] = w[(g & 63) * KCODES + (g >> 6)];
  if (g < KCODES) {
    // numpy axis-0 reduce: sequential over d, mul then add (no fma)
    float s = __fmul_rn(w[g], w[g]);
    for (int dd = 1; dd < DDIM; ++dd) {
      float v = w[dd * KCODES + g];
      s = __fadd_rn(s, __fmul_rn(v, v));
    }
    wsq[g] = s;
  }
}

// Each lane owns ONE full x-row in registers. Wave pair splits K (0..255 /
// 256..511); row half selected by wv>>1. B columns are wave-uniform -> SMEM.
template <int USE_WT, int USE_PARTS>
__global__ __launch_bounds__(256) void vq_main(
    const float* __restrict__ x, const float* __restrict__ w,
    const float* __restrict__ wT, const float* __restrict__ wsq,
    float* __restrict__ out_idx, float* __restrict__ out_zq,
    float* __restrict__ out_ze, float* __restrict__ lossOut) {
  __shared__ float dist_s[2][64];
  __shared__ int   kidx_s[2][64];
  __shared__ int   kfin_s[2][64];
  __shared__ float loss_s[4];

  const int tid = threadIdx.x;
  const int wv = tid >> 6;
  const int lane = tid & 63;
  const int rhalf = wv >> 1;   // row half within block
  const int khalf = wv & 1;    // code half
  const int row = blockIdx.x * 128 + rhalf * 64 + lane;
  const float* xr = x + (size_t)row * DDIM;

  // ---- load own row into registers (one-time) ----
  float a[64];
#pragma unroll
  for (int j = 0; j < 16; ++j) {
    float4 v = *(const float4*)(xr + j * 4);
    a[4 * j + 0] = v.x; a[4 * j + 1] = v.y;
    a[4 * j + 2] = v.z; a[4 * j + 3] = v.w;
  }

  // ---- sumf: numpy pairwise 8-accumulator scheme (bit-exact, as round 3) ----
  float rr[8];
#pragma unroll
  for (int j = 0; j < 8; ++j) rr[j] = __fmul_rn(a[j], a[j]);
#pragma unroll
  for (int blk = 1; blk < 8; ++blk)
#pragma unroll
    for (int j = 0; j < 8; ++j)
      rr[j] = __fadd_rn(rr[j], __fmul_rn(a[blk * 8 + j], a[blk * 8 + j]));
  const float sumf =
      __fadd_rn(__fadd_rn(__fadd_rn(rr[0], rr[1]), __fadd_rn(rr[2], rr[3])),
                __fadd_rn(__fadd_rn(rr[4], rr[5]), __fadd_rn(rr[6], rr[7])));

  // ---- K loop: 256 codes per wave, zero LDS, B via wave-uniform loads ----
  const int kBase = khalf * 256;
  float mind = 3.4e38f;
  int mink = kBase;
  for (int k = kBase; k < kBase + 256; ++k) {
    float dot = 0.f;
    float wsqk;
    if (USE_WT) {
      const float* bk = wT + ((size_t)k << 6);
#pragma unroll
      for (int d = 0; d < 64; ++d) dot = __builtin_fmaf(a[d], bk[d], dot);
      wsqk = wsq[k];
    } else {
      float bv[64];
#pragma unroll
      for (int d = 0; d < 64; ++d) bv[d] = w[d * KCODES + k];
#pragma unroll
      for (int d = 0; d < 64; ++d) dot = __builtin_fmaf(a[d], bv[d], dot);
      wsqk = __fmul_rn(bv[0], bv[0]);
#pragma unroll
      for (int d = 1; d < 64; ++d)
        wsqk = __fadd_rn(wsqk, __fmul_rn(bv[d], bv[d]));
    }
    // numpy tree: (sumf - 2*dot) + wsq, per-op rounding
    float dist = __fadd_rn(__fsub_rn(sumf, __fmul_rn(2.0f, dot)), wsqk);
    if (dist < mind) { mind = dist; mink = k; }  // strict <: first index wins
  }

  // ---- combine the two K-halves (tie -> lower k, i.e. khalf 0) ----
  if (khalf == 1) { dist_s[rhalf][lane] = mind; kidx_s[rhalf][lane] = mink; }
  __syncthreads();
  if (khalf == 0) {
    float od = dist_s[rhalf][lane];
    int ok = kidx_s[rhalf][lane];
    if (od < mind) { mind = od; mink = ok; }
    kfin_s[rhalf][lane] = mink;
  }
  __syncthreads();
  const int kf = kfin_s[rhalf][lane];

  if (khalf == 0) out_idx[row] = (float)kf;

  // ---- epilogue: both waves of the pair handle one d-half of the same rows ----
  float lsum = 0.f;
  const size_t go = (size_t)row * DDIM;
#define EPI_QUAD(J)                                                          \
  {                                                                          \
    float4 wv4;                                                              \
    if (USE_WT) {                                                            \
      wv4 = *(const float4*)(wT + ((size_t)kf << 6) + (J) * 4);              \
    } else {                                                                 \
      wv4 = make_float4(w[((J) * 4 + 0) * KCODES + kf],                      \
                        w[((J) * 4 + 1) * KCODES + kf],                      \
                        w[((J) * 4 + 2) * KCODES + kf],                      \
                        w[((J) * 4 + 3) * KCODES + kf]);                     \
    }                                                                        \
    float x0 = a[(J) * 4 + 0], x1 = a[(J) * 4 + 1];                          \
    float x2 = a[(J) * 4 + 2], x3 = a[(J) * 4 + 3];                          \
    float4 zq = make_float4(__fadd_rn(x0, __fsub_rn(wv4.x, x0)),             \
                            __fadd_rn(x1, __fsub_rn(wv4.y, x1)),             \
                            __fadd_rn(x2, __fsub_rn(wv4.z, x2)),             \
                            __fadd_rn(x3, __fsub_rn(wv4.w, x3)));            \
    *(float4*)(out_zq + go + (J) * 4) = zq;                                  \
    *(float4*)(out_ze + go + (J) * 4) = make_float4(x0, x1, x2, x3);         \
    float d0 = __fsub_rn(wv4.x, x0), d1 = __fsub_rn(wv4.y, x1);              \
    float d2 = __fsub_rn(wv4.z, x2), d3 = __fsub_rn(wv4.w, x3);              \
    lsum = __builtin_fmaf(d0, d0, lsum);                                     \
    lsum = __builtin_fmaf(d1, d1, lsum);                                     \
    lsum = __builtin_fmaf(d2, d2, lsum);                                     \
    lsum = __builtin_fmaf(d3, d3, lsum);                                     \
  }
  if (khalf == 0) {
    EPI_QUAD(0) EPI_QUAD(1) EPI_QUAD(2) EPI_QUAD(3)
    EPI_QUAD(4) EPI_QUAD(5) EPI_QUAD(6) EPI_QUAD(7)
  } else {
    EPI_QUAD(8)  EPI_QUAD(9)  EPI_QUAD(10) EPI_QUAD(11)
    EPI_QUAD(12) EPI_QUAD(13) EPI_QUAD(14) EPI_QUAD(15)
  }
#undef EPI_QUAD

#pragma unroll
  for (int s = 1; s < 64; s <<= 1) lsum += __shfl_xor(lsum, s);
  if (lane == 0) loss_s[wv] = lsum;
  __syncthreads();
  if (tid == 0) {
    float part = __fadd_rn(__fadd_rn(__fadd_rn(loss_s[0], loss_s[1]), loss_s[2]), loss_s[3]);
    if (USE_PARTS) lossOut[blockIdx.x] = part;
    else atomicAdd(lossOut, part);
  }
}

// loss = 2 * sum / (N*D) = sum * 2^-22
__global__ void vq_loss(const float* __restrict__ part, int npart,
                        float* __restrict__ out_loss) {
  float s = 0.f;
  for (int i = threadIdx.x; i < npart; i += 64) s += part[i];
#pragma unroll
  for (int t = 1; t < 64; t <<= 1) s += __shfl_xor(s, t);
  if (threadIdx.x == 0) out_loss[0] = s * (1.0f / 4194304.0f);
}

extern "C" void kernel_launch(void* const* d_in, const int* in_sizes, int n_in,
                              void* d_out, int out_size, void* d_ws, size_t ws_size,
                              hipStream_t stream) {
  const float* x = (const float*)d_in[0];
  const float* w = (const float*)d_in[1];
  float* ob = (float*)d_out;
  float* out_idx = ob;
  float* out_zq = ob + NROWS;
  float* out_ze = out_zq + (size_t)NROWS * DDIM;
  float* out_loss = out_ze + (size_t)NROWS * DDIM;
  float* wsf = (float*)d_ws;

  const size_t needParts = (size_t)(WS_AUX + NMAIN) * sizeof(float);  // 137216
  const size_t needCell  = (size_t)(WS_AUX + 1) * sizeof(float);      // 133124

  if (ws_size >= needParts) {
    vq_prep<<<128, 256, 0, stream>>>(w, wsf + WS_WT, wsf + WS_WSQ);
    vq_main<1, 1><<<NMAIN, 256, 0, stream>>>(x, w, wsf + WS_WT, wsf + WS_WSQ,
                                             out_idx, out_zq, out_ze, wsf + WS_AUX);
    vq_loss<<<1, 64, 0, stream>>>(wsf + WS_AUX, NMAIN, out_loss);
  } else if (ws_size >= needCell) {
    vq_prep<<<128, 256, 0, stream>>>(w, wsf + WS_WT, wsf + WS_WSQ);
    hipMemsetAsync(wsf + WS_AUX, 0, sizeof(float), stream);
    vq_main<1, 0><<<NMAIN, 256, 0, stream>>>(x, w, wsf + WS_WT, wsf + WS_WSQ,
                                             out_idx, out_zq, out_ze, wsf + WS_AUX);
    vq_loss<<<1, 64, 0, stream>>>(wsf + WS_AUX, 1, out_loss);
  } else {
    hipMemsetAsync(wsf, 0, sizeof(float), stream);
    vq_main<0, 0><<<NMAIN, 256, 0, stream>>>(x, w, nullptr, nullptr,
                                             out_idx, out_zq, out_ze, wsf);
    vq_loss<<<1, 64, 0, stream>>>(wsf, 1, out_loss);
  }
}

// Round 6
// 195.873 us; speedup vs baseline: 2.6663x; 2.6663x over previous
//
#include <hip/hip_runtime.h>

#define NROWS   131072
#define DDIM    64
#define KCODES  512
#define NBLOCKS 1024   // 128 rows per block

// ws float offsets (need (33280+1024)*4 = 137216 B; round 3 proved ws >= this)
#define WS_WT   0       // 32768 floats: wT[k][d]
#define WS_WSQ  32768   // 512 floats
#define WS_PART 33280   // 1024 floats

// r4-verified prep: wT[k][d] transpose + wsq in numpy axis-0 sequential order
__global__ void vq_prep(const float* __restrict__ w, float* __restrict__ wT,
                        float* __restrict__ wsq) {
  int g = blockIdx.x * 256 + threadIdx.x;  // g = k*64 + d, 32768 total
  wT[g] = w[(g & 63) * KCODES + (g >> 6)];
  if (g < KCODES) {
    float s = __fmul_rn(w[g], w[g]);
    for (int dd = 1; dd < DDIM; ++dd) {
      float v = w[dd * KCODES + g];
      s = __fadd_rn(s, __fmul_rn(v, v));
    }
    wsq[g] = s;
  }
}

template <int USE_WS>
__global__ __launch_bounds__(256) void vq_main(
    const float* __restrict__ x, const float* __restrict__ w,
    const float* __restrict__ wT, const float* __restrict__ wsq,
    float* __restrict__ out_idx, float* __restrict__ out_zq,
    float* __restrict__ out_ze, float* __restrict__ lossOut) {
  __shared__ float xT[4][32 * 64];   // per-wave x tile [d][row], stride 32 (r3 layout)
  __shared__ float sumf_s[4][32];
  __shared__ int   idx_s[4][32];
  __shared__ float lsum_s[4];

  const int tid = threadIdx.x;
  const int wv = tid >> 6;
  const int lane = tid & 63;
  const int r = lane >> 3;   // row-group 0..7 (4 rows)
  const int c = lane & 7;    // code-group 0..7 (8 codes)
  const int rowBase = (blockIdx.x * 4 + wv) * 32;
  const float* xblk = x + (size_t)rowBase * DDIM;

  // ---- stage x tile transposed (r3 verbatim; per-wave private slab) ----
#pragma unroll
  for (int j = 0; j < 8; ++j) {
    int off = j * 256 + lane * 4;
    float4 v = *(const float4*)(xblk + off);
    int row = off >> 6, d0 = off & 63;
    xT[wv][(d0 + 0) * 32 + row] = v.x;
    xT[wv][(d0 + 1) * 32 + row] = v.y;
    xT[wv][(d0 + 2) * 32 + row] = v.z;
    xT[wv][(d0 + 3) * 32 + row] = v.w;
  }
  __syncthreads();

  // ---- sumf per row: numpy pairwise 8-accumulator scheme (r3 verbatim) ----
  if (lane < 32) {
    float rr[8];
#pragma unroll
    for (int j = 0; j < 8; ++j) {
      float v = xT[wv][j * 32 + lane];
      rr[j] = __fmul_rn(v, v);
    }
#pragma unroll
    for (int blk = 1; blk < 8; ++blk)
#pragma unroll
      for (int j = 0; j < 8; ++j) {
        float v = xT[wv][(blk * 8 + j) * 32 + lane];
        rr[j] = __fadd_rn(rr[j], __fmul_rn(v, v));
      }
    float s01 = __fadd_rn(rr[0], rr[1]);
    float s23 = __fadd_rn(rr[2], rr[3]);
    float s45 = __fadd_rn(rr[4], rr[5]);
    float s67 = __fadd_rn(rr[6], rr[7]);
    sumf_s[wv][lane] = __fadd_rn(__fadd_rn(s01, s23), __fadd_rn(s45, s67));
  }
  __syncthreads();

  float sumf_r[4];
#pragma unroll
  for (int i = 0; i < 4; ++i) sumf_r[i] = sumf_s[wv][r * 4 + i];

  float minv[4] = {3.4e38f, 3.4e38f, 3.4e38f, 3.4e38f};
  int mink[4] = {0, 0, 0, 0};

  // ---- ct loop: barrier-free; A from per-wave LDS, B from global (L1) ----
  for (int ct = 0; ct < 8; ++ct) {
    const float* wrow = w + ct * 64 + c * 8;

    float acc[4][8];
#pragma unroll
    for (int i = 0; i < 4; ++i)
#pragma unroll
      for (int j = 0; j < 8; ++j) acc[i][j] = 0.f;

    // sequential-d single-accumulator FMA dot (bit-exact, r3 order)
#pragma unroll 4
    for (int d = 0; d < DDIM; ++d) {
      float4 a4 = *(const float4*)&xT[wv][d * 32 + r * 4];   // broadcast, conflict-free
      float4 b0 = *(const float4*)&wrow[d * KCODES];          // 256B/wave, L1-hit
      float4 b1 = *(const float4*)&wrow[d * KCODES + 4];
      float a[4] = {a4.x, a4.y, a4.z, a4.w};
      float b[8] = {b0.x, b0.y, b0.z, b0.w, b1.x, b1.y, b1.z, b1.w};
#pragma unroll
      for (int i = 0; i < 4; ++i)
#pragma unroll
        for (int j = 0; j < 8; ++j)
          acc[i][j] = __builtin_fmaf(a[i], b[j], acc[i][j]);
    }

    // wsq for this lane's 8 codes
    float sq[8];
    if (USE_WS) {
      float4 q0 = *(const float4*)&wsq[ct * 64 + c * 8];
      float4 q1 = *(const float4*)&wsq[ct * 64 + c * 8 + 4];
      sq[0] = q0.x; sq[1] = q0.y; sq[2] = q0.z; sq[3] = q0.w;
      sq[4] = q1.x; sq[5] = q1.y; sq[6] = q1.z; sq[7] = q1.w;
    } else {
#pragma unroll
      for (int j = 0; j < 8; ++j) {
        int k = ct * 64 + c * 8 + j;
        float v0 = w[k];
        float s = __fmul_rn(v0, v0);
        for (int dd = 1; dd < DDIM; ++dd) {
          float v = w[dd * KCODES + k];
          s = __fadd_rn(s, __fmul_rn(v, v));
        }
        sq[j] = s;
      }
    }

    // distances: numpy tree (sumf - 2*dot) + wsq, per-op rounding (r3 verbatim)
#pragma unroll
    for (int i = 0; i < 4; ++i) {
      float sf = sumf_r[i];
#pragma unroll
      for (int j = 0; j < 8; ++j) {
        float dist = __fadd_rn(__fsub_rn(sf, __fmul_rn(2.0f, acc[i][j])), sq[j]);
        int k = ct * 64 + c * 8 + j;
        if (dist < minv[i]) { minv[i] = dist; mink[i] = k; }  // strict <: first k wins
      }
    }
  }

  // ---- cross-lane argmin over the 8 code-groups (r3 verbatim; tie -> smaller k) ----
#pragma unroll
  for (int i = 0; i < 4; ++i) {
    float v = minv[i];
    int kk = mink[i];
    for (int s = 1; s < 8; s <<= 1) {
      float ov = __shfl_xor(v, s);
      int ok = __shfl_xor(kk, s);
      if (ov < v || (ov == v && ok < kk)) { v = ov; kk = ok; }
    }
    if (c == 0) idx_s[wv][r * 4 + i] = kk;
  }
  // idx_s[wv] produced and consumed by the same wave (r3-verified pattern)

  // ---- epilogue (r3 verbatim, wT gather): z_q_st, z_e, loss partial ----
  float lsum = 0.f;
  for (int rowi = 0; rowi < 32; ++rowi) {
    int k = idx_s[wv][rowi];
    size_t go = (size_t)(rowBase + rowi) * DDIM + lane;
    float xv = xblk[rowi * DDIM + lane];
    float wvv = USE_WS ? wT[k * DDIM + lane] : w[lane * KCODES + k];
    out_zq[go] = __fadd_rn(xv, __fsub_rn(wvv, xv));  // z_e + (z_q - z_e), per-op
    out_ze[go] = xv;
    float dd = __fsub_rn(wvv, xv);
    lsum = __builtin_fmaf(dd, dd, lsum);
  }
#pragma unroll
  for (int s = 1; s < 64; s <<= 1) lsum += __shfl_xor(lsum, s);
  if (lane == 0) lsum_s[wv] = lsum;
  __syncthreads();
  if (tid == 0) {
    float part = __fadd_rn(__fadd_rn(__fadd_rn(lsum_s[0], lsum_s[1]), lsum_s[2]), lsum_s[3]);
    if (USE_WS) lossOut[blockIdx.x] = part;
    else atomicAdd(lossOut, part);
  }
  if (lane < 32)
    out_idx[rowBase + lane] = (float)idx_s[wv][lane];
}

// loss = 2 * sum / (N*D) = sum * 2^-22  (r3 verbatim)
__global__ void vq_loss(const float* __restrict__ part, int npart,
                        float* __restrict__ out_loss) {
  float s = 0.f;
  for (int i = threadIdx.x; i < npart; i += 64) s += part[i];
#pragma unroll
  for (int t = 1; t < 64; t <<= 1) s += __shfl_xor(s, t);
  if (threadIdx.x == 0) out_loss[0] = s * (1.0f / 4194304.0f);
}

extern "C" void kernel_launch(void* const* d_in, const int* in_sizes, int n_in,
                              void* d_out, int out_size, void* d_ws, size_t ws_size,
                              hipStream_t stream) {
  const float* x = (const float*)d_in[0];
  const float* w = (const float*)d_in[1];
  float* ob = (float*)d_out;
  float* out_idx = ob;
  float* out_zq = ob + NROWS;
  float* out_ze = out_zq + (size_t)NROWS * DDIM;
  float* out_loss = out_ze + (size_t)NROWS * DDIM;
  float* wsf = (float*)d_ws;

  const size_t need = (size_t)(WS_PART + NBLOCKS) * sizeof(float);  // 137216 B
  if (ws_size >= need) {
    vq_prep<<<128, 256, 0, stream>>>(w, wsf + WS_WT, wsf + WS_WSQ);
    vq_main<1><<<NBLOCKS, 256, 0, stream>>>(x, w, wsf + WS_WT, wsf + WS_WSQ,
                                            out_idx, out_zq, out_ze, wsf + WS_PART);
    vq_loss<<<1, 64, 0, stream>>>(wsf + WS_PART, NBLOCKS, out_loss);
  } else {
    // fallback: no ws dependency; loss via pre-zeroed atomic cell in out_loss
    hipMemsetAsync(out_loss, 0, sizeof(float), stream);
    vq_main<0><<<NBLOCKS, 256, 0, stream>>>(x, w, nullptr, nullptr,
                                            out_idx, out_zq, out_ze, out_loss);
    vq_loss<<<1, 64, 0, stream>>>(out_loss, 1, out_loss);
  }
}

// Round 7
// 171.493 us; speedup vs baseline: 3.0453x; 1.1422x over previous
//
#include <hip/hip_runtime.h>
#include <hip/hip_bf16.h>

#define NROWS   131072
#define DDIM    64
#define KCODES  512
#define NBLOCKS 1024   // 128 rows per block

// ws float offsets
#define WS_WT    0        // 32768 floats: wT[k][d] fp32
#define WS_WSQ   32768    // 512 floats
#define WS_PART  33280    // 1024 floats
#define WS_WTH   34304    // 16384 float-slots = 32768 ushort: bf16-hi of wT
#define WS_WTL   50688    // 16384 float-slots: bf16-lo of wT
#define WS_NEED_MFMA ((size_t)(WS_WTL + 16384) * sizeof(float))  // 268288 B
#define WS_NEED_FALL ((size_t)(WS_PART + NBLOCKS) * sizeof(float))  // 137216 B

#define CAND_CAP 16
#define THRESH   0.04f

typedef __attribute__((ext_vector_type(8))) short short8;
typedef __attribute__((ext_vector_type(4))) float f32x4;

static __device__ __forceinline__ unsigned short f2bf(float v) {
  union { __hip_bfloat16 b; unsigned short u; } cv;
  cv.b = __float2bfloat16(v);
  return cv.u;
}
static __device__ __forceinline__ float bf2f(unsigned short u) {
  union { float f; unsigned v; } r;
  r.v = ((unsigned)u) << 16;
  return r.f;
}

// wT[k][d] transpose + wsq in numpy axis-0 sequential order (verified r3-r6)
__global__ void vq_prep_base(const float* __restrict__ w, float* __restrict__ wT,
                             float* __restrict__ wsq) {
  int g = blockIdx.x * 256 + threadIdx.x;  // g = k*64 + d
  wT[g] = w[(g & 63) * KCODES + (g >> 6)];
  if (g < KCODES) {
    float s = __fmul_rn(w[g], w[g]);
    for (int dd = 1; dd < DDIM; ++dd) {
      float v = w[dd * KCODES + g];
      s = __fadd_rn(s, __fmul_rn(v, v));
    }
    wsq[g] = s;
  }
}

// bf16 hi/lo split of wT (runs after vq_prep_base on same stream)
__global__ void vq_prep_bf16(const float* __restrict__ wT,
                             unsigned short* __restrict__ wTh,
                             unsigned short* __restrict__ wTl) {
  int g = blockIdx.x * 256 + threadIdx.x;
  float v = wT[g];
  unsigned short h = f2bf(v);
  wTh[g] = h;
  wTl[g] = f2bf(v - bf2f(h));
}

// ---------------- MFMA main: approx distances + exact rescore ----------------
__global__ __launch_bounds__(256) void vq_mfma(
    const float* __restrict__ x, const float* __restrict__ wT,
    const float* __restrict__ wsq, const unsigned short* __restrict__ wTh,
    const unsigned short* __restrict__ wTl, float* __restrict__ out_idx,
    float* __restrict__ out_zq, float* __restrict__ out_ze,
    float* __restrict__ lossPart) {
  __shared__ float xf[128 * 68];     // fp32 x tile, stride 68 (16B-aligned, bank-spread)
  __shared__ float sumf_s[128];
  __shared__ int   idx_s[128];
  __shared__ int   cnt[128];
  __shared__ int   cand[128][CAND_CAP];
  __shared__ float lsum_s[4];

  const int tid = threadIdx.x;
  const int wv = tid >> 6;
  const int lane = tid & 63;
  const int lr = lane & 15;   // A-row / B-col / C-col within tile
  const int kg = lane >> 4;   // k-group (0..3)
  const int rowBase = blockIdx.x * 128;
  const float* xb = x + (size_t)rowBase * DDIM;

  // ---- stage x fp32 tile ----
#pragma unroll
  for (int j = 0; j < 8; ++j) {
    int off = j * 1024 + tid * 4;
    float4 v = *(const float4*)(xb + off);
    int row = off >> 6, d0 = off & 63;
    *(float4*)&xf[row * 68 + d0] = v;
  }
  if (tid < 128) cnt[tid] = 0;
  __syncthreads();

  // ---- A fragments (hi/lo bf16) in registers for the whole K sweep ----
  // assumed layout: lane holds A[row = lane&15][k = (lane>>4)*8 + j]
  short8 ah[2][2], al[2][2];
#pragma unroll
  for (int m = 0; m < 2; ++m)
#pragma unroll
    for (int kb = 0; kb < 2; ++kb) {
      const float* src = &xf[(wv * 32 + m * 16 + lr) * 68 + kb * 32 + kg * 8];
      short8 h, l;
#pragma unroll
      for (int j = 0; j < 8; ++j) {
        float v = src[j];
        unsigned short hu = f2bf(v);
        h[j] = (short)hu;
        l[j] = (short)f2bf(v - bf2f(hu));
      }
      ah[m][kb] = h;
      al[m][kb] = l;
    }

  // ---- sumf per row: numpy pairwise 8-accumulator (verified r3) ----
  if (lane < 32) {
    int row = wv * 32 + lane;
    const float* xr = &xf[row * 68];
    float rr[8];
#pragma unroll
    for (int j = 0; j < 8; ++j) rr[j] = __fmul_rn(xr[j], xr[j]);
#pragma unroll
    for (int blk = 1; blk < 8; ++blk)
#pragma unroll
      for (int j = 0; j < 8; ++j) {
        float v = xr[blk * 8 + j];
        rr[j] = __fadd_rn(rr[j], __fmul_rn(v, v));
      }
    float s01 = __fadd_rn(rr[0], rr[1]);
    float s23 = __fadd_rn(rr[2], rr[3]);
    float s45 = __fadd_rn(rr[4], rr[5]);
    float s67 = __fadd_rn(rr[6], rr[7]);
    sumf_s[row] = __fadd_rn(__fadd_rn(s01, s23), __fadd_rn(s45, s67));
  }

  // ---- pass 1: running per-(m,reg) min of score = wsq - 2*dot_approx ----
  float rmin[2][4];
#pragma unroll
  for (int m = 0; m < 2; ++m)
#pragma unroll
    for (int q = 0; q < 4; ++q) rmin[m][q] = 3.4e38f;

  for (int n = 0; n < 32; ++n) {
    const int kcol = n * 16 + lr;
    short8 bh0 = *(const short8*)(wTh + kcol * 64 + kg * 8);
    short8 bh1 = *(const short8*)(wTh + kcol * 64 + 32 + kg * 8);
    short8 bl0 = *(const short8*)(wTl + kcol * 64 + kg * 8);
    short8 bl1 = *(const short8*)(wTl + kcol * 64 + 32 + kg * 8);
    float wsqk = wsq[kcol];
#pragma unroll
    for (int m = 0; m < 2; ++m) {
      f32x4 acc = {0.f, 0.f, 0.f, 0.f};
      acc = __builtin_amdgcn_mfma_f32_16x16x32_bf16(ah[m][0], bh0, acc, 0, 0, 0);
      acc = __builtin_amdgcn_mfma_f32_16x16x32_bf16(al[m][0], bh0, acc, 0, 0, 0);
      acc = __builtin_amdgcn_mfma_f32_16x16x32_bf16(ah[m][0], bl0, acc, 0, 0, 0);
      acc = __builtin_amdgcn_mfma_f32_16x16x32_bf16(ah[m][1], bh1, acc, 0, 0, 0);
      acc = __builtin_amdgcn_mfma_f32_16x16x32_bf16(al[m][1], bh1, acc, 0, 0, 0);
      acc = __builtin_amdgcn_mfma_f32_16x16x32_bf16(ah[m][1], bl1, acc, 0, 0, 0);
#pragma unroll
      for (int q = 0; q < 4; ++q) {
        float sc = __builtin_fmaf(-2.0f, acc[q], wsqk);
        rmin[m][q] = fminf(rmin[m][q], sc);
      }
    }
  }
  // row-min across the 16 cols (lanes sharing kg)
#pragma unroll
  for (int m = 0; m < 2; ++m)
#pragma unroll
    for (int q = 0; q < 4; ++q) {
      float v = rmin[m][q];
#pragma unroll
      for (int s = 1; s < 16; s <<= 1) v = fminf(v, __shfl_xor(v, s));
      rmin[m][q] = v;
    }

  // ---- pass 2: bitwise-identical recompute, collect candidates <= min + T ----
  for (int n = 0; n < 32; ++n) {
    const int kcol = n * 16 + lr;
    short8 bh0 = *(const short8*)(wTh + kcol * 64 + kg * 8);
    short8 bh1 = *(const short8*)(wTh + kcol * 64 + 32 + kg * 8);
    short8 bl0 = *(const short8*)(wTl + kcol * 64 + kg * 8);
    short8 bl1 = *(const short8*)(wTl + kcol * 64 + 32 + kg * 8);
    float wsqk = wsq[kcol];
#pragma unroll
    for (int m = 0; m < 2; ++m) {
      f32x4 acc = {0.f, 0.f, 0.f, 0.f};
      acc = __builtin_amdgcn_mfma_f32_16x16x32_bf16(ah[m][0], bh0, acc, 0, 0, 0);
      acc = __builtin_amdgcn_mfma_f32_16x16x32_bf16(al[m][0], bh0, acc, 0, 0, 0);
      acc = __builtin_amdgcn_mfma_f32_16x16x32_bf16(ah[m][0], bl0, acc, 0, 0, 0);
      acc = __builtin_amdgcn_mfma_f32_16x16x32_bf16(ah[m][1], bh1, acc, 0, 0, 0);
      acc = __builtin_amdgcn_mfma_f32_16x16x32_bf16(al[m][1], bh1, acc, 0, 0, 0);
      acc = __builtin_amdgcn_mfma_f32_16x16x32_bf16(ah[m][1], bl1, acc, 0, 0, 0);
#pragma unroll
      for (int q = 0; q < 4; ++q) {
        float sc = __builtin_fmaf(-2.0f, acc[q], wsqk);
        if (sc <= rmin[m][q] + THRESH) {
          int row = wv * 32 + m * 16 + kg * 4 + q;  // verified C layout
          int slot = atomicAdd(&cnt[row], 1);
          if (slot < CAND_CAP) cand[row][slot] = kcol;
        }
      }
    }
  }
  __syncthreads();

  // ---- exact rescore among candidates (bit-exact numpy semantics) ----
  for (int rg = 0; rg < 8; ++rg) {
    const int lrow = wv * 32 + rg * 4 + kg;  // 16 lanes (lr) per row
    const int cn = cnt[lrow];
    const float* xr = &xf[lrow * 68];
    const float sf = sumf_s[lrow];
    if (cn <= CAND_CAP) {
      float bd = 3.4e38f;
      int bk = 0x7fffffff;
      if (lr < cn) {
        int k = cand[lrow][lr];
        const float* wk = wT + k * DDIM;
        float dot = 0.f;
#pragma unroll
        for (int d = 0; d < DDIM; ++d) dot = __builtin_fmaf(xr[d], wk[d], dot);
        bd = __fadd_rn(__fsub_rn(sf, __fmul_rn(2.0f, dot)), wsq[k]);
        bk = k;
      }
#pragma unroll
      for (int s = 1; s < 16; s <<= 1) {  // lexicographic: strict <, tie -> lower k
        float od = __shfl_xor(bd, s);
        int ok = __shfl_xor(bk, s);
        if (od < bd || (od == bd && ok < bk)) { bd = od; bk = ok; }
      }
      if (lr == 0) idx_s[lrow] = bk;
    } else if (lr == 0) {  // overflow fallback (~never): full exact scan
      float bd = 3.4e38f;
      int bk = 0;
      for (int k = 0; k < KCODES; ++k) {
        const float* wk = wT + k * DDIM;
        float dot = 0.f;
        for (int d = 0; d < DDIM; ++d) dot = __builtin_fmaf(xr[d], wk[d], dot);
        float dist = __fadd_rn(__fsub_rn(sf, __fmul_rn(2.0f, dot)), wsq[k]);
        if (dist < bd) { bd = dist; bk = k; }
      }
      idx_s[lrow] = bk;
    }
  }
  __syncthreads();

  // ---- epilogue (r3-verified): z_q_st, z_e, loss partial, indices ----
  float lsum = 0.f;
  const int rowBaseW = rowBase + wv * 32;
  for (int rowi = 0; rowi < 32; ++rowi) {
    int k = idx_s[wv * 32 + rowi];
    size_t go = (size_t)(rowBaseW + rowi) * DDIM + lane;
    float xv = xf[(wv * 32 + rowi) * 68 + lane];
    float wvv = wT[k * DDIM + lane];
    out_zq[go] = __fadd_rn(xv, __fsub_rn(wvv, xv));  // z_e + (z_q - z_e)
    out_ze[go] = xv;
    float dd = __fsub_rn(wvv, xv);
    lsum = __builtin_fmaf(dd, dd, lsum);
  }
#pragma unroll
  for (int s = 1; s < 64; s <<= 1) lsum += __shfl_xor(lsum, s);
  if (lane == 0) lsum_s[wv] = lsum;
  __syncthreads();
  if (tid == 0) {
    float part = __fadd_rn(__fadd_rn(__fadd_rn(lsum_s[0], lsum_s[1]), lsum_s[2]), lsum_s[3]);
    lossPart[blockIdx.x] = part;
  }
  if (lane < 32)
    out_idx[rowBaseW + lane] = (float)idx_s[wv * 32 + lane];
}

// ---------------- fallback: round-3 verified kernel (152 us) ----------------
template <int USE_WT, int LOSS_ATOMIC>
__global__ __launch_bounds__(256) void vq_fb(
    const float* __restrict__ x, const float* __restrict__ w,
    const float* __restrict__ wT,
    float* __restrict__ out_idx, float* __restrict__ out_zq,
    float* __restrict__ out_ze, float* __restrict__ lossOut) {
  __shared__ float xT[4][32 * 64];
  __shared__ float wtile[64 * 64];
  __shared__ float __attribute__((aligned(16))) sq_s[64];
  __shared__ float sumf_s[4][32];
  __shared__ int   idx_s[4][32];
  __shared__ float lsum_s[4];

  const int tid = threadIdx.x;
  const int wv = tid >> 6;
  const int lane = tid & 63;
  const int r = lane >> 3;
  const int c = lane & 7;
  const int rowBase = (blockIdx.x * 4 + wv) * 32;
  const float* xblk = x + (size_t)rowBase * DDIM;

#pragma unroll
  for (int j = 0; j < 8; ++j) {
    int off = j * 256 + lane * 4;
    float4 v = *(const float4*)(xblk + off);
    int row = off >> 6, d0 = off & 63;
    xT[wv][(d0 + 0) * 32 + row] = v.x;
    xT[wv][(d0 + 1) * 32 + row] = v.y;
    xT[wv][(d0 + 2) * 32 + row] = v.z;
    xT[wv][(d0 + 3) * 32 + row] = v.w;
  }
  __syncthreads();

  if (lane < 32) {
    float rr[8];
#pragma unroll
    for (int j = 0; j < 8; ++j) {
      float v = xT[wv][j * 32 + lane];
      rr[j] = __fmul_rn(v, v);
    }
#pragma unroll
    for (int blk = 1; blk < 8; ++blk)
#pragma unroll
      for (int j = 0; j < 8; ++j) {
        float v = xT[wv][(blk * 8 + j) * 32 + lane];
        rr[j] = __fadd_rn(rr[j], __fmul_rn(v, v));
      }
    float s01 = __fadd_rn(rr[0], rr[1]);
    float s23 = __fadd_rn(rr[2], rr[3]);
    float s45 = __fadd_rn(rr[4], rr[5]);
    float s67 = __fadd_rn(rr[6], rr[7]);
    sumf_s[wv][lane] = __fadd_rn(__fadd_rn(s01, s23), __fadd_rn(s45, s67));
  }

  float minv[4] = {3.4e38f, 3.4e38f, 3.4e38f, 3.4e38f};
  int mink[4] = {0, 0, 0, 0};

  for (int ct = 0; ct < 8; ++ct) {
#pragma unroll
    for (int j = 0; j < 4; ++j) {
      int off = j * 1024 + tid * 4;
      int d0 = off >> 6, kk = off & 63;
      *(float4*)&wtile[off] = *(const float4*)&w[d0 * KCODES + ct * 64 + kk];
    }
    __syncthreads();

    if (tid < 64) {
      float v0 = wtile[tid];
      float s = __fmul_rn(v0, v0);
      for (int d = 1; d < 64; ++d) {
        float v = wtile[d * 64 + tid];
        s = __fadd_rn(s, __fmul_rn(v, v));
      }
      sq_s[tid] = s;
    }

    float acc[4][8];
#pragma unroll
    for (int i = 0; i < 4; ++i)
#pragma unroll
      for (int j = 0; j < 8; ++j) acc[i][j] = 0.f;

#pragma unroll 4
    for (int d = 0; d < DDIM; ++d) {
      float4 a4 = *(const float4*)&xT[wv][d * 32 + r * 4];
      float4 b0 = *(const float4*)&wtile[d * 64 + c * 8];
      float4 b1 = *(const float4*)&wtile[d * 64 + c * 8 + 4];
      float a[4] = {a4.x, a4.y, a4.z, a4.w};
      float b[8] = {b0.x, b0.y, b0.z, b0.w, b1.x, b1.y, b1.z, b1.w};
#pragma unroll
      for (int i = 0; i < 4; ++i)
#pragma unroll
        for (int j = 0; j < 8; ++j)
          acc[i][j] = __builtin_fmaf(a[i], b[j], acc[i][j]);
    }
    __syncthreads();

#pragma unroll
    for (int i = 0; i < 4; ++i) {
      float sf = sumf_s[wv][r * 4 + i];
#pragma unroll
      for (int j = 0; j < 8; ++j) {
        float dist = __fadd_rn(__fsub_rn(sf, __fmul_rn(2.0f, acc[i][j])), sq_s[c * 8 + j]);
        int k = ct * 64 + c * 8 + j;
        if (dist < minv[i]) { minv[i] = dist; mink[i] = k; }
      }
    }
  }

#pragma unroll
  for (int i = 0; i < 4; ++i) {
    float v = minv[i];
    int kk = mink[i];
    for (int s = 1; s < 8; s <<= 1) {
      float ov = __shfl_xor(v, s);
      int ok = __shfl_xor(kk, s);
      if (ov < v || (ov == v && ok < kk)) { v = ov; kk = ok; }
    }
    if (c == 0) idx_s[wv][r * 4 + i] = kk;
  }

  float lsum = 0.f;
  for (int rowi = 0; rowi < 32; ++rowi) {
    int k = idx_s[wv][rowi];
    size_t go = (size_t)(rowBase + rowi) * DDIM + lane;
    float xv = xblk[rowi * DDIM + lane];
    float wvv = USE_WT ? wT[k * DDIM + lane] : w[lane * KCODES + k];
    out_zq[go] = __fadd_rn(xv, __fsub_rn(wvv, xv));
    out_ze[go] = xv;
    float dd = __fsub_rn(wvv, xv);
    lsum = __builtin_fmaf(dd, dd, lsum);
  }
#pragma unroll
  for (int s = 1; s < 64; s <<= 1) lsum += __shfl_xor(lsum, s);
  if (lane == 0) lsum_s[wv] = lsum;
  __syncthreads();
  if (tid == 0) {
    float part = __fadd_rn(__fadd_rn(__fadd_rn(lsum_s[0], lsum_s[1]), lsum_s[2]), lsum_s[3]);
    if (LOSS_ATOMIC) atomicAdd(lossOut, part);
    else lossOut[blockIdx.x] = part;
  }
  if (lane < 32)
    out_idx[rowBase + lane] = (float)idx_s[wv][lane];
}

// loss = 2 * sum / (N*D) = sum * 2^-22
__global__ void vq_loss(const float* __restrict__ part, int npart,
                        float* __restrict__ out_loss) {
  float s = 0.f;
  for (int i = threadIdx.x; i < npart; i += 64) s += part[i];
#pragma unroll
  for (int t = 1; t < 64; t <<= 1) s += __shfl_xor(s, t);
  if (threadIdx.x == 0) out_loss[0] = s * (1.0f / 4194304.0f);
}

extern "C" void kernel_launch(void* const* d_in, const int* in_sizes, int n_in,
                              void* d_out, int out_size, void* d_ws, size_t ws_size,
                              hipStream_t stream) {
  const float* x = (const float*)d_in[0];
  const float* w = (const float*)d_in[1];
  float* ob = (float*)d_out;
  float* out_idx = ob;
  float* out_zq = ob + NROWS;
  float* out_ze = out_zq + (size_t)NROWS * DDIM;
  float* out_loss = out_ze + (size_t)NROWS * DDIM;
  float* wsf = (float*)d_ws;

  if (ws_size >= WS_NEED_MFMA) {
    vq_prep_base<<<128, 256, 0, stream>>>(w, wsf + WS_WT, wsf + WS_WSQ);
    vq_prep_bf16<<<128, 256, 0, stream>>>(wsf + WS_WT,
                                          (unsigned short*)(wsf + WS_WTH),
                                          (unsigned short*)(wsf + WS_WTL));
    vq_mfma<<<NBLOCKS, 256, 0, stream>>>(x, wsf + WS_WT, wsf + WS_WSQ,
                                         (const unsigned short*)(wsf + WS_WTH),
                                         (const unsigned short*)(wsf + WS_WTL),
                                         out_idx, out_zq, out_ze, wsf + WS_PART);
    vq_loss<<<1, 64, 0, stream>>>(wsf + WS_PART, NBLOCKS, out_loss);
  } else if (ws_size >= WS_NEED_FALL) {
    vq_prep_base<<<128, 256, 0, stream>>>(w, wsf + WS_WT, wsf + WS_WSQ);
    vq_fb<1, 0><<<NBLOCKS, 256, 0, stream>>>(x, w, wsf + WS_WT, out_idx,
                                             out_zq, out_ze, wsf + WS_PART);
    vq_loss<<<1, 64, 0, stream>>>(wsf + WS_PART, NBLOCKS, out_loss);
  } else {
    hipMemsetAsync(out_loss, 0, sizeof(float), stream);
    vq_fb<0, 1><<<NBLOCKS, 256, 0, stream>>>(x, w, nullptr, out_idx,
                                             out_zq, out_ze, out_loss);
    vq_loss<<<1, 64, 0, stream>>>(out_loss, 1, out_loss);
  }
}